// Round 5
// baseline (1819.955 us; speedup 1.0000x reference)
//
#include <hip/hip_runtime.h>

typedef unsigned long long u64;
typedef unsigned int u32;
typedef unsigned short ushort_t;
typedef __attribute__((ext_vector_type(8))) short short8;
typedef __attribute__((ext_vector_type(4))) float fx4;

#define F_DIM 1024
#define H_DIM 2048
#define NFOUT 4
#define WS_W1T_OFF (1u << 20)

// ---------------------------------------------------------------------------
// bf16 helpers (RNE) and 3-way split: x = p0+p1+p2, |p1|<=2^-9|x|, |p2|<=2^-18|x|
// ---------------------------------------------------------------------------
__device__ __forceinline__ ushort_t f2bf(float x)
{
    union { float f; u32 u; } c; c.f = x;
    u32 b = c.u;
    u32 r = b + 0x7FFFu + ((b >> 16) & 1u);
    return (ushort_t)(r >> 16);
}
__device__ __forceinline__ float bf2f(ushort_t h)
{
    union { u32 u; float f; } c; c.u = ((u32)h) << 16;
    return c.f;
}
__device__ __forceinline__ void split3(float x, ushort_t& u0, ushort_t& u1, ushort_t& u2)
{
    u0 = f2bf(x);
    float r1 = x - bf2f(u0);
    u1 = f2bf(r1);
    float r2 = r1 - bf2f(u1);
    u2 = f2bf(r2);
}

// ---------------------------------------------------------------------------
// k_w1split: W1[k][h] fp32 -> 3 bf16 planes TRANSPOSED: w1t[p][h][k] (k-contig)
// ---------------------------------------------------------------------------
__global__ __launch_bounds__(256)
void k_w1split(const float* __restrict__ W1, ushort_t* __restrict__ w1t)
{
    __shared__ __align__(16) ushort_t LT[3][64][72];
    const int t = threadIdx.x;
    const int bk = blockIdx.x >> 5;
    const int bh = blockIdx.x & 31;
    const int k0 = bk * 64, h0 = bh * 64;
    const int kk = t >> 4, hb = (t & 15) * 4;
    #pragma unroll
    for (int j = 0; j < 4; j++) {
        int row = kk + j * 16;
        float4 v = *(const float4*)(W1 + (size_t)(k0 + row) * H_DIM + h0 + hb);
        float xs[4] = { v.x, v.y, v.z, v.w };
        #pragma unroll
        for (int c = 0; c < 4; c++) {
            ushort_t u0, u1, u2;
            split3(xs[c], u0, u1, u2);
            LT[0][hb + c][row] = u0;
            LT[1][hb + c][row] = u1;
            LT[2][hb + c][row] = u2;
        }
    }
    __syncthreads();
    const int hl = t >> 2, sg = t & 3;
    #pragma unroll
    for (int p = 0; p < 3; p++)
        #pragma unroll
        for (int q = 0; q < 2; q++) {
            int ks = sg * 16 + q * 8;
            *(short8*)(w1t + (size_t)p * (H_DIM * (size_t)F_DIM)
                       + (size_t)(h0 + hl) * F_DIM + k0 + ks) =
                *(const short8*)&LT[p][hl][ks];
        }
}

// ---------------------------------------------------------------------------
// k_filt_mfma v2: 512 threads (8 waves = 2/SIMD), block tile 64 rows x 256 hid,
// wave tile 32x64, split-6 bf16 MFMA, T2 swizzle, T14 async reg-staging
// (loads for it+1 issued before MFMA of it). GEMM2 fused per hc-tile.
// Dynamic LDS: A planes 24KB | B planes 96KB | W2s 4KB = 124KB (1 block/CU).
// ---------------------------------------------------------------------------
__device__ __forceinline__ fx4 mfma16(short8 a, short8 b, fx4 c)
{
    return __builtin_amdgcn_mfma_f32_16x16x32_bf16(a, b, c, 0, 0, 0);
}

#define AP_BYTES (3 * 64 * 128)      // 24576
#define BP_BYTES (3 * 256 * 128)     // 98304
#define SM_BYTES (AP_BYTES + BP_BYTES + 256 * 4 * 4)
#define HPITCH 261

__global__ __launch_bounds__(512, 2)
void k_filt_mfma(const float* __restrict__ X, const ushort_t* __restrict__ w1t,
                 const float* __restrict__ b1, const float* __restrict__ W2,
                 const float* __restrict__ b2, float* __restrict__ out, int N)
{
    extern __shared__ char smem[];
    char* Ac = smem;
    char* Bc = smem + AP_BYTES;
    float* W2s = (float*)(smem + AP_BYTES + BP_BYTES);
    float* hid = (float*)Bc;         // overlay: 64*261*4 = 66816 <= 98304
    float* part = (float*)Ac;        // overlay: 64*4*2*4 = 2048 <= 24576

    const int t = threadIdx.x;
    const int lane = t & 63;
    const int w = t >> 6;
    const int wr = (w & 1) * 32;
    const int wc = (w >> 1) * 64;    // 0..192
    const int r0 = blockIdx.x * 64;
    const int l15 = lane & 15, l4 = lane >> 4;

    const int arow = t >> 3;                 // 0..63
    const int ak8  = (t & 7) * 8;            // k elems 0..56
    const bool arow_ok = (r0 + arow) < N;
    const int brow = t >> 1;                 // 0..255
    const int bseg = (t & 1) * 64;           // bytes 0/64

    const int g2row = lane;
    const int g2nf  = w & 3;
    const int g2seg = w >> 2;

    float Afl[8];
    short8 Bv[12];
    fx4 acc[2][4];
    float pacc = 0.f;
    #pragma unroll
    for (int i = 0; i < 2; i++)
        #pragma unroll
        for (int j = 0; j < 4; j++) acc[i][j] = (fx4)(0.f);

    // ---- prologue: load (hc=0, kc=0) into regs ----
    {
        if (arow_ok) {
            float4 v0 = *(const float4*)(X + (size_t)(r0 + arow) * F_DIM + ak8);
            float4 v1 = *(const float4*)(X + (size_t)(r0 + arow) * F_DIM + ak8 + 4);
            Afl[0] = v0.x; Afl[1] = v0.y; Afl[2] = v0.z; Afl[3] = v0.w;
            Afl[4] = v1.x; Afl[5] = v1.y; Afl[6] = v1.z; Afl[7] = v1.w;
        } else {
            #pragma unroll
            for (int j = 0; j < 8; j++) Afl[j] = 0.f;
        }
        #pragma unroll
        for (int p = 0; p < 3; p++)
            #pragma unroll
            for (int q = 0; q < 4; q++)
                Bv[p * 4 + q] = *(const short8*)(w1t + (size_t)p * (H_DIM * (size_t)F_DIM)
                                 + (size_t)brow * F_DIM + (bseg + q * 16) / 2);
    }

    for (int it = 0; it < 128; ++it) {
        const int hc = it >> 4, kc = it & 15;

        // ---- split current A (VALU) ----
        ushort_t s0[8], s1[8], s2[8];
        #pragma unroll
        for (int j = 0; j < 8; j++) split3(Afl[j], s0[j], s1[j], s2[j]);
        short8 Au0, Au1, Au2;
        #pragma unroll
        for (int j = 0; j < 8; j++) { Au0[j] = (short)s0[j]; Au1[j] = (short)s1[j]; Au2[j] = (short)s2[j]; }

        __syncthreads();   // barrier 1: prior LDS readers (MFMA / GEMM2) done

        // ---- ds_write phase ----
        {
            const int aswz = (arow & 7) << 4;
            const int abyte = (ak8 * 2);
            *(short8*)(Ac + 0 * 8192 + arow * 128 + (abyte ^ aswz)) = Au0;
            *(short8*)(Ac + 1 * 8192 + arow * 128 + (abyte ^ aswz)) = Au1;
            *(short8*)(Ac + 2 * 8192 + arow * 128 + (abyte ^ aswz)) = Au2;
            const int bswz = (brow & 7) << 4;
            #pragma unroll
            for (int p = 0; p < 3; p++)
                #pragma unroll
                for (int q = 0; q < 4; q++)
                    *(short8*)(Bc + p * 32768 + brow * 128 + ((bseg + q * 16) ^ bswz)) = Bv[p * 4 + q];
            if (kc == 0 && t < 256)
                *(float4*)&W2s[t * 4] = *(const float4*)(W2 + ((size_t)hc * 256 + t) * NFOUT);
        }

        // ---- issue next loads (fly under MFMA) ----
        if (it + 1 < 128) {
            const int hn = (it + 1) >> 4, kn = (it + 1) & 15;
            if (arow_ok) {
                float4 v0 = *(const float4*)(X + (size_t)(r0 + arow) * F_DIM + kn * 64 + ak8);
                float4 v1 = *(const float4*)(X + (size_t)(r0 + arow) * F_DIM + kn * 64 + ak8 + 4);
                Afl[0] = v0.x; Afl[1] = v0.y; Afl[2] = v0.z; Afl[3] = v0.w;
                Afl[4] = v1.x; Afl[5] = v1.y; Afl[6] = v1.z; Afl[7] = v1.w;
            }
            #pragma unroll
            for (int p = 0; p < 3; p++)
                #pragma unroll
                for (int q = 0; q < 4; q++)
                    Bv[p * 4 + q] = *(const short8*)(w1t + (size_t)p * (H_DIM * (size_t)F_DIM)
                                     + (size_t)(hn * 256 + brow) * F_DIM + kn * 64 + (bseg + q * 16) / 2);
        }

        __syncthreads();   // barrier 2: LDS tile for kc ready

        // ---- MFMA: split-6 ----
        #pragma unroll
        for (int sub = 0; sub < 2; ++sub) {
            const int kb = sub * 64 + l4 * 16;
            const int sw = (l15 & 7) << 4;
            short8 a[2][3];
            #pragma unroll
            for (int rr = 0; rr < 2; ++rr) {
                const int row = wr + rr * 16 + l15;
                #pragma unroll
                for (int p = 0; p < 3; p++)
                    a[rr][p] = *(const short8*)(Ac + p * 8192 + row * 128 + (kb ^ sw));
            }
            #pragma unroll
            for (int cf = 0; cf < 4; ++cf) {
                const int hrow = wc + cf * 16 + l15;
                short8 bb0 = *(const short8*)(Bc + 0 * 32768 + hrow * 128 + (kb ^ sw));
                short8 bb1 = *(const short8*)(Bc + 1 * 32768 + hrow * 128 + (kb ^ sw));
                short8 bb2 = *(const short8*)(Bc + 2 * 32768 + hrow * 128 + (kb ^ sw));
                #pragma unroll
                for (int rr = 0; rr < 2; ++rr) {
                    fx4 c = acc[rr][cf];
                    c = mfma16(a[rr][0], bb0, c);
                    c = mfma16(a[rr][0], bb1, c);
                    c = mfma16(a[rr][1], bb0, c);
                    c = mfma16(a[rr][0], bb2, c);
                    c = mfma16(a[rr][1], bb1, c);
                    c = mfma16(a[rr][2], bb0, c);
                    acc[rr][cf] = c;
                }
            }
        }

        if (kc == 15) {
            __syncthreads();   // MFMA readers done; hid overlays Bc
            // ---- hid: +b1, relu (C/D: col=lane&15, row=(lane>>4)*4+reg) ----
            #pragma unroll
            for (int rr = 0; rr < 2; ++rr)
                #pragma unroll
                for (int cf = 0; cf < 4; ++cf) {
                    const int hl = wc + cf * 16 + l15;
                    const float bias1 = b1[hc * 256 + hl];
                    #pragma unroll
                    for (int g = 0; g < 4; g++) {
                        const int rl = wr + rr * 16 + l4 * 4 + g;
                        hid[rl * HPITCH + hl] = fmaxf(acc[rr][cf][g] + bias1, 0.f);
                    }
                    acc[rr][cf] = (fx4)(0.f);
                }
            __syncthreads();
            // ---- GEMM2 partial: wave-w threads: row=lane, nf=w&3, seg=w>>2 ----
            {
                const float* hp = hid + g2row * HPITCH + g2seg * 128;
                const int hb = g2seg * 128;
                #pragma unroll 16
                for (int j = 0; j < 128; j++)
                    pacc = fmaf(hp[j], W2s[(hb + j) * 4 + g2nf], pacc);
            }
        }
    }

    __syncthreads();
    part[g2row * 8 + g2nf * 2 + g2seg] = pacc;
    __syncthreads();
    if (t < 256) {
        const int row = t >> 2, nf = t & 3;
        const float s = part[row * 8 + nf * 2 + 0] + part[row * 8 + nf * 2 + 1];
        const int rg = r0 + row;
        if (rg < N) out[(size_t)rg * NFOUT + nf] = s + b2[nf];
    }
}

// ---------------------------------------------------------------------------
// FALLBACK fp32 k_filt (only if ws too small for w1t planes)
// ---------------------------------------------------------------------------
#define BM 64
#define BH 64
#define KCH 64
#define LROW 68

__global__ __launch_bounds__(256, 2)
void k_filt(const float* __restrict__ X, const float* __restrict__ W1,
            const float* __restrict__ b1, const float* __restrict__ W2,
            const float* __restrict__ b2, float* __restrict__ out, int N)
{
    __shared__ float Xs[KCH * LROW];
    __shared__ float Ws[KCH * LROW];
    __shared__ float W2s[BH * NFOUT];
    const int t = threadIdx.x;
    const int r0 = blockIdx.x * BM;
    const int tr = t >> 4, tc = t & 15;
    const int orow = t >> 2, onf = t & 3;
    float fchain = 0.0f;
    for (int hc = 0; hc < H_DIM; hc += BH) {
        float acc[4][4];
        #pragma unroll
        for (int i = 0; i < 4; i++)
            #pragma unroll
            for (int j = 0; j < 4; j++) acc[i][j] = 0.0f;
        for (int kc = 0; kc < F_DIM; kc += KCH) {
            {
                const int rowq = t >> 4, kkq = t & 15;
                float xv[4][4];
                #pragma unroll
                for (int j = 0; j < 4; j++) {
                    int r = r0 + rowq * 4 + j;
                    float4 v = (r < N) ? *(const float4*)(X + (size_t)r * F_DIM + kc + kkq * 4)
                                       : make_float4(0.f, 0.f, 0.f, 0.f);
                    xv[j][0] = v.x; xv[j][1] = v.y; xv[j][2] = v.z; xv[j][3] = v.w;
                }
                #pragma unroll
                for (int j = 0; j < 4; j++)
                    *(float4*)&Xs[(kkq * 4 + j) * LROW + rowq * 4] =
                        make_float4(xv[0][j], xv[1][j], xv[2][j], xv[3][j]);
            }
            {
                const int hq = t & 15;
                #pragma unroll
                for (int q = 0; q < 4; q++) {
                    int kk = (t >> 4) + q * 16;
                    *(float4*)&Ws[kk * LROW + hq * 4] =
                        *(const float4*)(W1 + (size_t)(kc + kk) * H_DIM + hc + hq * 4);
                }
            }
            __syncthreads();
            #pragma unroll 8
            for (int kk = 0; kk < KCH; kk++) {
                float4 xv = *(float4*)&Xs[kk * LROW + tr * 4];
                float4 wv = *(float4*)&Ws[kk * LROW + tc * 4];
                acc[0][0] = fmaf(xv.x, wv.x, acc[0][0]); acc[0][1] = fmaf(xv.x, wv.y, acc[0][1]);
                acc[0][2] = fmaf(xv.x, wv.z, acc[0][2]); acc[0][3] = fmaf(xv.x, wv.w, acc[0][3]);
                acc[1][0] = fmaf(xv.y, wv.x, acc[1][0]); acc[1][1] = fmaf(xv.y, wv.y, acc[1][1]);
                acc[1][2] = fmaf(xv.y, wv.z, acc[1][2]); acc[1][3] = fmaf(xv.y, wv.w, acc[1][3]);
                acc[2][0] = fmaf(xv.z, wv.x, acc[2][0]); acc[2][1] = fmaf(xv.z, wv.y, acc[2][1]);
                acc[2][2] = fmaf(xv.z, wv.z, acc[2][2]); acc[2][3] = fmaf(xv.z, wv.w, acc[2][3]);
                acc[3][0] = fmaf(xv.w, wv.x, acc[3][0]); acc[3][1] = fmaf(xv.w, wv.y, acc[3][1]);
                acc[3][2] = fmaf(xv.w, wv.z, acc[3][2]); acc[3][3] = fmaf(xv.w, wv.w, acc[3][3]);
            }
            __syncthreads();
        }
        {
            float4 bv = *(const float4*)(b1 + hc + tc * 4);
            #pragma unroll
            for (int i = 0; i < 4; i++) {
                float4 hv;
                hv.x = fmaxf(acc[i][0] + bv.x, 0.f);
                hv.y = fmaxf(acc[i][1] + bv.y, 0.f);
                hv.z = fmaxf(acc[i][2] + bv.z, 0.f);
                hv.w = fmaxf(acc[i][3] + bv.w, 0.f);
                *(float4*)&Ws[(tr * 4 + i) * LROW + tc * 4] = hv;
            }
            if (t < BH)
                *(float4*)&W2s[t * 4] = *(const float4*)(W2 + (size_t)(hc + t) * NFOUT);
        }
        __syncthreads();
        #pragma unroll 16
        for (int hh = 0; hh < BH; hh++)
            fchain = fmaf(Ws[orow * LROW + hh], W2s[hh * 4 + onf], fchain);
        __syncthreads();
    }
    {
        int r = r0 + orow;
        if (r < N) out[(size_t)r * NFOUT + onf] = fchain + b2[onf];
    }
}

// ---------------------------------------------------------------------------
__global__ void k_prep(u32* __restrict__ rank, int N)
{
    int g = blockIdx.x * blockDim.x + threadIdx.x;
    if (g < 4 * N) rank[g] = 0u;
}

// ---------------------------------------------------------------------------
#define JTILE 2048

__global__ __launch_bounds__(256)
void k_rank(const float* __restrict__ filt, u32* __restrict__ rank,
            int N, int nchunk)
{
    __shared__ float4 lds[JTILE];
    const int chunk = blockIdx.x % nchunk;
    const int jslice = blockIdx.x / nchunk;
    const int jt = jslice * JTILE;
    const int i = chunk * 256 + threadIdx.x;
    const bool iok = i < N;
    float4 vi = iok ? *(const float4*)(filt + (size_t)i * 4)
                    : make_float4(0.f, 0.f, 0.f, 0.f);
    for (int s = 0; s < JTILE; s += 256) {
        int j = jt + s + threadIdx.x;
        lds[s + threadIdx.x] = (j < N)
            ? *(const float4*)(filt + (size_t)j * 4)
            : make_float4(INFINITY, INFINITY, INFINITY, INFINITY);
    }
    __syncthreads();
    int c0 = 0, c1 = 0, c2 = 0, c3 = 0;
    #pragma unroll 4
    for (int jj = 0; jj < JTILE; jj++) {
        float4 vj = lds[jj];
        int j = jt + jj;
        bool jlt = j < i;
        c0 += (vj.x < vi.x) || (vj.x == vi.x && jlt);
        c1 += (vj.y < vi.y) || (vj.y == vi.y && jlt);
        c2 += (vj.z < vi.z) || (vj.z == vi.z && jlt);
        c3 += (vj.w < vi.w) || (vj.w == vi.w && jlt);
    }
    if (iok) {
        atomicAdd(&rank[0 * N + i], (u32)c0);
        atomicAdd(&rank[1 * N + i], (u32)c1);
        atomicAdd(&rank[2 * N + i], (u32)c2);
        atomicAdd(&rank[3 * N + i], (u32)c3);
    }
}

// ---------------------------------------------------------------------------
// Triplet merge tree in LDS (one 1024-thr block per filtration)
// ---------------------------------------------------------------------------
__device__ __forceinline__ u32 lds_aload(u32* p)
{
    return __hip_atomic_load(p, __ATOMIC_RELAXED, __HIP_MEMORY_SCOPE_WORKGROUP);
}

__device__ __forceinline__ u32 rep_walk32(u32* S, u32 u, u32 t, u32& sv_out)
{
    u32 sv = lds_aload(&S[u]);
    while ((sv >> 16) <= t) {
        u = sv & 0xFFFFu;
        sv = lds_aload(&S[u]);
    }
    sv_out = sv;
    return u;
}

__device__ void do_merge32(u32* S, u32 u, u32 v, u32 t)
{
    for (int guard = 0; guard < (1 << 22); guard++) {
        u32 svu, svv;
        u = rep_walk32(S, u, t, svu);
        v = rep_walk32(S, v, t, svv);
        if (u == v) return;
        if (u < v) { u32 tm = u; u = v; v = tm; u32 ts = svu; svu = svv; svv = ts; }
        u32 s = svu >> 16;
        if (s <= t) continue;
        u32 des = (t << 16) | v;
        u32 old = atomicCAS(&S[u], svu, des);
        if (old == svu) {
            if (s == 0xFFFFu) return;
            u = v; v = old & 0xFFFFu;
            t = s;
        }
    }
}

__global__ __launch_bounds__(1024, 1)
void k_merge4(const int* __restrict__ eidx, const u32* __restrict__ rank,
              float* __restrict__ dg, int N, int E)
{
    extern __shared__ u32 S[];
    const int f = blockIdx.x;
    const u32* rk = rank + (size_t)f * N;

    for (int u = threadIdx.x; u < N; u += blockDim.x)
        S[u] = (0xFFFFu << 16) | (u32)u;
    __syncthreads();

    for (int e = threadIdx.x; e < E; e += blockDim.x) {
        u32 a = rk[eidx[e]];
        u32 b = rk[eidx[E + e]];
        if (a < b) do_merge32(S, a, b, b);
    }
    __syncthreads();

    for (int r = threadIdx.x; r < N; r += blockDim.x) {
        u32 s = S[r] >> 16;
        float death = (s == 0xFFFFu) ? 3.0e38f : (float)s;
        dg[(size_t)f * N * 2 + (size_t)r * 2 + 0] = (float)r;
        dg[(size_t)f * N * 2 + (size_t)r * 2 + 1] = death;
    }
}

// ---------------------------------------------------------------------------
extern "C" void kernel_launch(void* const* d_in, const int* in_sizes, int n_in,
                              void* d_out, int out_size, void* d_ws, size_t ws_size,
                              hipStream_t stream)
{
    const float* X  = (const float*)d_in[0];
    const int*   EI = (const int*)d_in[1];
    const float* W1 = (const float*)d_in[2];
    const float* b1 = (const float*)d_in[3];
    const float* W2 = (const float*)d_in[4];
    const float* b2 = (const float*)d_in[5];
    const int N = in_sizes[0] / F_DIM;
    const int E = in_sizes[1] / 2;

    float* out = (float*)d_out;
    float* dg  = out + (size_t)N * NFOUT;
    u32* rank  = (u32*)d_ws;

    static bool attr_set = false;
    if (!attr_set) {
        (void)hipFuncSetAttribute((const void*)k_merge4,
                                  hipFuncAttributeMaxDynamicSharedMemorySize,
                                  160 * 1024);
        (void)hipFuncSetAttribute((const void*)k_filt_mfma,
                                  hipFuncAttributeMaxDynamicSharedMemorySize,
                                  160 * 1024);
        attr_set = true;
    }

    k_prep<<<(4 * N + 255) / 256, 256, 0, stream>>>(rank, N);

    const size_t w1t_need = (size_t)WS_W1T_OFF + 3ull * H_DIM * F_DIM * 2;
    if (ws_size >= w1t_need) {
        ushort_t* w1t = (ushort_t*)((char*)d_ws + WS_W1T_OFF);
        k_w1split<<<512, 256, 0, stream>>>(W1, w1t);
        k_filt_mfma<<<(N + 63) / 64, 512, SM_BYTES, stream>>>(X, w1t, b1, W2, b2, out, N);
    } else {
        k_filt<<<(N + BM - 1) / BM, 256, 0, stream>>>(X, W1, b1, W2, b2, out, N);
    }

    const int nchunk = (N + 255) / 256;
    const int njt    = (N + JTILE - 1) / JTILE;
    k_rank<<<nchunk * njt, 256, 0, stream>>>(out, rank, N, nchunk);
    k_merge4<<<4, 1024, (size_t)N * sizeof(u32), stream>>>(EI, rank, dg, N, E);
}

// Round 6
// 1602.655 us; speedup vs baseline: 1.1356x; 1.1356x over previous
//
#include <hip/hip_runtime.h>

typedef unsigned long long u64;
typedef unsigned int u32;
typedef unsigned short ushort_t;
typedef __attribute__((ext_vector_type(8))) short short8;
typedef __attribute__((ext_vector_type(4))) float fx4;

#define F_DIM 1024
#define H_DIM 2048
#define NFOUT 4
#define WS_W1T_OFF (1u << 20)

// ---------------------------------------------------------------------------
// bf16 helpers (RNE) and 3-way split: x = p0+p1+p2, |p1|<=2^-9|x|, |p2|<=2^-18|x|
// ---------------------------------------------------------------------------
__device__ __forceinline__ ushort_t f2bf(float x)
{
    union { float f; u32 u; } c; c.f = x;
    u32 b = c.u;
    u32 r = b + 0x7FFFu + ((b >> 16) & 1u);
    return (ushort_t)(r >> 16);
}
__device__ __forceinline__ float bf2f(ushort_t h)
{
    union { u32 u; float f; } c; c.u = ((u32)h) << 16;
    return c.f;
}
__device__ __forceinline__ void split3(float x, ushort_t& u0, ushort_t& u1, ushort_t& u2)
{
    u0 = f2bf(x);
    float r1 = x - bf2f(u0);
    u1 = f2bf(r1);
    float r2 = r1 - bf2f(u1);
    u2 = f2bf(r2);
}

// ---------------------------------------------------------------------------
// k_w1split: W1[k][h] fp32 -> 3 bf16 planes TRANSPOSED: w1t[p][h][k] (k-contig)
// ---------------------------------------------------------------------------
__global__ __launch_bounds__(256)
void k_w1split(const float* __restrict__ W1, ushort_t* __restrict__ w1t)
{
    __shared__ __align__(16) ushort_t LT[3][64][72];
    const int t = threadIdx.x;
    const int bk = blockIdx.x >> 5;
    const int bh = blockIdx.x & 31;
    const int k0 = bk * 64, h0 = bh * 64;
    const int kk = t >> 4, hb = (t & 15) * 4;
    #pragma unroll
    for (int j = 0; j < 4; j++) {
        int row = kk + j * 16;
        float4 v = *(const float4*)(W1 + (size_t)(k0 + row) * H_DIM + h0 + hb);
        float xs[4] = { v.x, v.y, v.z, v.w };
        #pragma unroll
        for (int c = 0; c < 4; c++) {
            ushort_t u0, u1, u2;
            split3(xs[c], u0, u1, u2);
            LT[0][hb + c][row] = u0;
            LT[1][hb + c][row] = u1;
            LT[2][hb + c][row] = u2;
        }
    }
    __syncthreads();
    const int hl = t >> 2, sg = t & 3;
    #pragma unroll
    for (int p = 0; p < 3; p++)
        #pragma unroll
        for (int q = 0; q < 2; q++) {
            int ks = sg * 16 + q * 8;
            *(short8*)(w1t + (size_t)p * (H_DIM * (size_t)F_DIM)
                       + (size_t)(h0 + hl) * F_DIM + k0 + ks) =
                *(const short8*)&LT[p][hl][ks];
        }
}

// ---------------------------------------------------------------------------
// k_filt_mfma v3: block tile 128 rows x 256 hid, 512 threads = 8 waves of
// 64x64 (4x4 16x16 frags) -> grid 157 (single round, no tail), FLOP/LDS-byte
// +50% vs v2. Split-6 bf16 MFMA, T2 swizzle, T14 reg-staged prefetch.
// LDS: A 48KB | B 96KB | W2s 4KB = 148KB. hid overlays A|B (130KB).
// ---------------------------------------------------------------------------
__device__ __forceinline__ fx4 mfma16(short8 a, short8 b, fx4 c)
{
    return __builtin_amdgcn_mfma_f32_16x16x32_bf16(a, b, c, 0, 0, 0);
}

#define AP_BYTES (3 * 128 * 128)     // 49152
#define BP_BYTES (3 * 256 * 128)     // 98304
#define W2_OFF   (AP_BYTES + BP_BYTES)
#define SM_BYTES (W2_OFF + 256 * 4 * 4)
#define HPITCH 260

__global__ __launch_bounds__(512, 2)
void k_filt_mfma(const float* __restrict__ X, const ushort_t* __restrict__ w1t,
                 const float* __restrict__ b1, const float* __restrict__ W2,
                 const float* __restrict__ b2, float* __restrict__ out, int N)
{
    extern __shared__ char smem[];
    char* Ac = smem;
    char* Bc = smem + AP_BYTES;
    float* W2s = (float*)(smem + W2_OFF);
    float* hid = (float*)smem;       // overlay: 128*260*4 = 133120 <= 147456

    const int t = threadIdx.x;
    const int lane = t & 63;
    const int w = t >> 6;
    const int wr = (w >> 2) * 64;    // 0,64
    const int wc = (w & 3) * 64;     // 0..192
    const int r0 = blockIdx.x * 128;
    const int l15 = lane & 15, l4 = lane >> 4;
    const int fsw = (l15 & 7) << 4;  // fragment-read swizzle

    const int arow = t >> 2;                 // 0..127
    const int aq   = (t & 3);                // 16 k-elems each
    const bool arow_ok = (r0 + arow) < N;
    const int brow = t >> 1;                 // 0..255
    const int bseg = (t & 1) * 64;           // byte half of 128B row

    const int orow = t >> 2;                 // GEMM2: 128 rows x 4 nf = 512
    const int onf  = t & 3;

    float Afl[16];
    short8 Bv[12];
    fx4 acc[4][4];
    float pacc = 0.f;
    #pragma unroll
    for (int i = 0; i < 4; i++)
        #pragma unroll
        for (int j = 0; j < 4; j++) acc[i][j] = (fx4)(0.f);

    // ---- prologue: load (hc=0, kc=0) ----
    {
        if (arow_ok) {
            #pragma unroll
            for (int q = 0; q < 4; q++) {
                float4 v = *(const float4*)(X + (size_t)(r0 + arow) * F_DIM + aq * 16 + q * 4);
                Afl[q * 4 + 0] = v.x; Afl[q * 4 + 1] = v.y;
                Afl[q * 4 + 2] = v.z; Afl[q * 4 + 3] = v.w;
            }
        } else {
            #pragma unroll
            for (int j = 0; j < 16; j++) Afl[j] = 0.f;
        }
        #pragma unroll
        for (int p = 0; p < 3; p++)
            #pragma unroll
            for (int q = 0; q < 4; q++)
                Bv[p * 4 + q] = *(const short8*)(w1t + (size_t)p * (H_DIM * (size_t)F_DIM)
                                 + (size_t)brow * F_DIM + bseg / 2 + q * 8);
    }

    for (int it = 0; it < 128; ++it) {
        const int hc = it >> 4, kc = it & 15;

        // ---- split current A (VALU) ----
        ushort_t s0[16], s1[16], s2[16];
        #pragma unroll
        for (int j = 0; j < 16; j++) split3(Afl[j], s0[j], s1[j], s2[j]);

        __syncthreads();   // barrier 1: prior LDS readers done

        // ---- ds_write phase ----
        {
            const int aswz = (arow & 7) << 4;
            #pragma unroll
            for (int p = 0; p < 3; p++) {
                const ushort_t* sp = (p == 0) ? s0 : (p == 1) ? s1 : s2;
                #pragma unroll
                for (int h = 0; h < 2; h++) {
                    short8 pk;
                    #pragma unroll
                    for (int i = 0; i < 8; i++) pk[i] = (short)sp[h * 8 + i];
                    *(short8*)(Ac + p * 16384 + arow * 128 + ((aq * 32 + h * 16) ^ aswz)) = pk;
                }
            }
            const int bswz = (brow & 7) << 4;
            #pragma unroll
            for (int p = 0; p < 3; p++)
                #pragma unroll
                for (int q = 0; q < 4; q++)
                    *(short8*)(Bc + p * 32768 + brow * 128 + ((bseg + q * 16) ^ bswz)) = Bv[p * 4 + q];
            if (kc == 0 && t < 256)
                *(float4*)&W2s[t * 4] = *(const float4*)(W2 + ((size_t)hc * 256 + t) * NFOUT);
        }

        // ---- issue next loads (fly under MFMA) ----
        if (it + 1 < 128) {
            const int hn = (it + 1) >> 4, kn = (it + 1) & 15;
            if (arow_ok) {
                #pragma unroll
                for (int q = 0; q < 4; q++) {
                    float4 v = *(const float4*)(X + (size_t)(r0 + arow) * F_DIM + kn * 64 + aq * 16 + q * 4);
                    Afl[q * 4 + 0] = v.x; Afl[q * 4 + 1] = v.y;
                    Afl[q * 4 + 2] = v.z; Afl[q * 4 + 3] = v.w;
                }
            }
            #pragma unroll
            for (int p = 0; p < 3; p++)
                #pragma unroll
                for (int q = 0; q < 4; q++)
                    Bv[p * 4 + q] = *(const short8*)(w1t + (size_t)p * (H_DIM * (size_t)F_DIM)
                                     + (size_t)(hn * 256 + brow) * F_DIM + kn * 64 + bseg / 2 + q * 8);
        }

        __syncthreads();   // barrier 2: LDS tile ready

        // ---- MFMA: split-6, 64x64 wave tile ----
        #pragma unroll
        for (int sub = 0; sub < 2; ++sub) {
            const int kb = sub * 64 + l4 * 16;
            short8 b[4][3];
            #pragma unroll
            for (int cf = 0; cf < 4; ++cf) {
                const int hrow = wc + cf * 16 + l15;
                #pragma unroll
                for (int p = 0; p < 3; p++)
                    b[cf][p] = *(const short8*)(Bc + p * 32768 + hrow * 128 + (kb ^ fsw));
            }
            #pragma unroll
            for (int rr = 0; rr < 4; ++rr) {
                const int row = wr + rr * 16 + l15;
                short8 a0 = *(const short8*)(Ac + 0 * 16384 + row * 128 + (kb ^ fsw));
                short8 a1 = *(const short8*)(Ac + 1 * 16384 + row * 128 + (kb ^ fsw));
                short8 a2 = *(const short8*)(Ac + 2 * 16384 + row * 128 + (kb ^ fsw));
                #pragma unroll
                for (int cf = 0; cf < 4; ++cf) {
                    fx4 c = acc[rr][cf];
                    c = mfma16(a0, b[cf][0], c);
                    c = mfma16(a0, b[cf][1], c);
                    c = mfma16(a1, b[cf][0], c);
                    c = mfma16(a0, b[cf][2], c);
                    c = mfma16(a1, b[cf][1], c);
                    c = mfma16(a2, b[cf][0], c);
                    acc[rr][cf] = c;
                }
            }
        }

        if (kc == 15) {
            __syncthreads();   // all MFMA reads done; hid overlays A|B
            // ---- hid: +b1, relu (C/D: col=lane&15, row=(lane>>4)*4+reg) ----
            #pragma unroll
            for (int rr = 0; rr < 4; ++rr)
                #pragma unroll
                for (int cf = 0; cf < 4; ++cf) {
                    const int hl = wc + cf * 16 + l15;
                    const float bias1 = b1[hc * 256 + hl];
                    #pragma unroll
                    for (int g = 0; g < 4; g++) {
                        const int rl = wr + rr * 16 + l4 * 4 + g;
                        hid[rl * HPITCH + hl] = fmaxf(acc[rr][cf][g] + bias1, 0.f);
                    }
                    acc[rr][cf] = (fx4)(0.f);
                }
            __syncthreads();
            // ---- GEMM2: thread (row, nf) full 256-h ascending chain ----
            {
                const float* hp = hid + orow * HPITCH;
                #pragma unroll 16
                for (int j = 0; j < 256; j++)
                    pacc = fmaf(hp[j], W2s[j * 4 + onf], pacc);
            }
        }
    }

    {
        const int rg = r0 + orow;
        if (rg < N) out[(size_t)rg * NFOUT + onf] = pacc + b2[onf];
    }
}

// ---------------------------------------------------------------------------
// FALLBACK fp32 k_filt (only if ws too small for w1t planes)
// ---------------------------------------------------------------------------
#define BM 64
#define BH 64
#define KCH 64
#define LROW 68

__global__ __launch_bounds__(256, 2)
void k_filt(const float* __restrict__ X, const float* __restrict__ W1,
            const float* __restrict__ b1, const float* __restrict__ W2,
            const float* __restrict__ b2, float* __restrict__ out, int N)
{
    __shared__ float Xs[KCH * LROW];
    __shared__ float Ws[KCH * LROW];
    __shared__ float W2s[BH * NFOUT];
    const int t = threadIdx.x;
    const int r0 = blockIdx.x * BM;
    const int tr = t >> 4, tc = t & 15;
    const int orow = t >> 2, onf = t & 3;
    float fchain = 0.0f;
    for (int hc = 0; hc < H_DIM; hc += BH) {
        float acc[4][4];
        #pragma unroll
        for (int i = 0; i < 4; i++)
            #pragma unroll
            for (int j = 0; j < 4; j++) acc[i][j] = 0.0f;
        for (int kc = 0; kc < F_DIM; kc += KCH) {
            {
                const int rowq = t >> 4, kkq = t & 15;
                float xv[4][4];
                #pragma unroll
                for (int j = 0; j < 4; j++) {
                    int r = r0 + rowq * 4 + j;
                    float4 v = (r < N) ? *(const float4*)(X + (size_t)r * F_DIM + kc + kkq * 4)
                                       : make_float4(0.f, 0.f, 0.f, 0.f);
                    xv[j][0] = v.x; xv[j][1] = v.y; xv[j][2] = v.z; xv[j][3] = v.w;
                }
                #pragma unroll
                for (int j = 0; j < 4; j++)
                    *(float4*)&Xs[(kkq * 4 + j) * LROW + rowq * 4] =
                        make_float4(xv[0][j], xv[1][j], xv[2][j], xv[3][j]);
            }
            {
                const int hq = t & 15;
                #pragma unroll
                for (int q = 0; q < 4; q++) {
                    int kk = (t >> 4) + q * 16;
                    *(float4*)&Ws[kk * LROW + hq * 4] =
                        *(const float4*)(W1 + (size_t)(kc + kk) * H_DIM + hc + hq * 4);
                }
            }
            __syncthreads();
            #pragma unroll 8
            for (int kk = 0; kk < KCH; kk++) {
                float4 xv = *(float4*)&Xs[kk * LROW + tr * 4];
                float4 wv = *(float4*)&Ws[kk * LROW + tc * 4];
                acc[0][0] = fmaf(xv.x, wv.x, acc[0][0]); acc[0][1] = fmaf(xv.x, wv.y, acc[0][1]);
                acc[0][2] = fmaf(xv.x, wv.z, acc[0][2]); acc[0][3] = fmaf(xv.x, wv.w, acc[0][3]);
                acc[1][0] = fmaf(xv.y, wv.x, acc[1][0]); acc[1][1] = fmaf(xv.y, wv.y, acc[1][1]);
                acc[1][2] = fmaf(xv.y, wv.z, acc[1][2]); acc[1][3] = fmaf(xv.y, wv.w, acc[1][3]);
                acc[2][0] = fmaf(xv.z, wv.x, acc[2][0]); acc[2][1] = fmaf(xv.z, wv.y, acc[2][1]);
                acc[2][2] = fmaf(xv.z, wv.z, acc[2][2]); acc[2][3] = fmaf(xv.z, wv.w, acc[2][3]);
                acc[3][0] = fmaf(xv.w, wv.x, acc[3][0]); acc[3][1] = fmaf(xv.w, wv.y, acc[3][1]);
                acc[3][2] = fmaf(xv.w, wv.z, acc[3][2]); acc[3][3] = fmaf(xv.w, wv.w, acc[3][3]);
            }
            __syncthreads();
        }
        {
            float4 bv = *(const float4*)(b1 + hc + tc * 4);
            #pragma unroll
            for (int i = 0; i < 4; i++) {
                float4 hv;
                hv.x = fmaxf(acc[i][0] + bv.x, 0.f);
                hv.y = fmaxf(acc[i][1] + bv.y, 0.f);
                hv.z = fmaxf(acc[i][2] + bv.z, 0.f);
                hv.w = fmaxf(acc[i][3] + bv.w, 0.f);
                *(float4*)&Ws[(tr * 4 + i) * LROW + tc * 4] = hv;
            }
            if (t < BH)
                *(float4*)&W2s[t * 4] = *(const float4*)(W2 + (size_t)(hc + t) * NFOUT);
        }
        __syncthreads();
        #pragma unroll 16
        for (int hh = 0; hh < BH; hh++)
            fchain = fmaf(Ws[orow * LROW + hh], W2s[hh * 4 + onf], fchain);
        __syncthreads();
    }
    {
        int r = r0 + orow;
        if (r < N) out[(size_t)r * NFOUT + onf] = fchain + b2[onf];
    }
}

// ---------------------------------------------------------------------------
__global__ void k_prep(u32* __restrict__ rank, int N)
{
    int g = blockIdx.x * blockDim.x + threadIdx.x;
    if (g < 4 * N) rank[g] = 0u;
}

// ---------------------------------------------------------------------------
#define JTILE 2048

__global__ __launch_bounds__(256)
void k_rank(const float* __restrict__ filt, u32* __restrict__ rank,
            int N, int nchunk)
{
    __shared__ float4 lds[JTILE];
    const int chunk = blockIdx.x % nchunk;
    const int jslice = blockIdx.x / nchunk;
    const int jt = jslice * JTILE;
    const int i = chunk * 256 + threadIdx.x;
    const bool iok = i < N;
    float4 vi = iok ? *(const float4*)(filt + (size_t)i * 4)
                    : make_float4(0.f, 0.f, 0.f, 0.f);
    for (int s = 0; s < JTILE; s += 256) {
        int j = jt + s + threadIdx.x;
        lds[s + threadIdx.x] = (j < N)
            ? *(const float4*)(filt + (size_t)j * 4)
            : make_float4(INFINITY, INFINITY, INFINITY, INFINITY);
    }
    __syncthreads();
    int c0 = 0, c1 = 0, c2 = 0, c3 = 0;
    #pragma unroll 4
    for (int jj = 0; jj < JTILE; jj++) {
        float4 vj = lds[jj];
        int j = jt + jj;
        bool jlt = j < i;
        c0 += (vj.x < vi.x) || (vj.x == vi.x && jlt);
        c1 += (vj.y < vi.y) || (vj.y == vi.y && jlt);
        c2 += (vj.z < vi.z) || (vj.z == vi.z && jlt);
        c3 += (vj.w < vi.w) || (vj.w == vi.w && jlt);
    }
    if (iok) {
        atomicAdd(&rank[0 * N + i], (u32)c0);
        atomicAdd(&rank[1 * N + i], (u32)c1);
        atomicAdd(&rank[2 * N + i], (u32)c2);
        atomicAdd(&rank[3 * N + i], (u32)c3);
    }
}

// ---------------------------------------------------------------------------
// Triplet merge tree in LDS (one 1024-thr block per filtration)
// ---------------------------------------------------------------------------
__device__ __forceinline__ u32 lds_aload(u32* p)
{
    return __hip_atomic_load(p, __ATOMIC_RELAXED, __HIP_MEMORY_SCOPE_WORKGROUP);
}

__device__ __forceinline__ u32 rep_walk32(u32* S, u32 u, u32 t, u32& sv_out)
{
    u32 sv = lds_aload(&S[u]);
    while ((sv >> 16) <= t) {
        u = sv & 0xFFFFu;
        sv = lds_aload(&S[u]);
    }
    sv_out = sv;
    return u;
}

__device__ void do_merge32(u32* S, u32 u, u32 v, u32 t)
{
    for (int guard = 0; guard < (1 << 22); guard++) {
        u32 svu, svv;
        u = rep_walk32(S, u, t, svu);
        v = rep_walk32(S, v, t, svv);
        if (u == v) return;
        if (u < v) { u32 tm = u; u = v; v = tm; u32 ts = svu; svu = svv; svv = ts; }
        u32 s = svu >> 16;
        if (s <= t) continue;
        u32 des = (t << 16) | v;
        u32 old = atomicCAS(&S[u], svu, des);
        if (old == svu) {
            if (s == 0xFFFFu) return;
            u = v; v = old & 0xFFFFu;
            t = s;
        }
    }
}

__global__ __launch_bounds__(1024, 1)
void k_merge4(const int* __restrict__ eidx, const u32* __restrict__ rank,
              float* __restrict__ dg, int N, int E)
{
    extern __shared__ u32 S[];
    const int f = blockIdx.x;
    const u32* rk = rank + (size_t)f * N;

    for (int u = threadIdx.x; u < N; u += blockDim.x)
        S[u] = (0xFFFFu << 16) | (u32)u;
    __syncthreads();

    for (int e = threadIdx.x; e < E; e += blockDim.x) {
        u32 a = rk[eidx[e]];
        u32 b = rk[eidx[E + e]];
        if (a < b) do_merge32(S, a, b, b);
    }
    __syncthreads();

    for (int r = threadIdx.x; r < N; r += blockDim.x) {
        u32 s = S[r] >> 16;
        float death = (s == 0xFFFFu) ? 3.0e38f : (float)s;
        dg[(size_t)f * N * 2 + (size_t)r * 2 + 0] = (float)r;
        dg[(size_t)f * N * 2 + (size_t)r * 2 + 1] = death;
    }
}

// ---------------------------------------------------------------------------
extern "C" void kernel_launch(void* const* d_in, const int* in_sizes, int n_in,
                              void* d_out, int out_size, void* d_ws, size_t ws_size,
                              hipStream_t stream)
{
    const float* X  = (const float*)d_in[0];
    const int*   EI = (const int*)d_in[1];
    const float* W1 = (const float*)d_in[2];
    const float* b1 = (const float*)d_in[3];
    const float* W2 = (const float*)d_in[4];
    const float* b2 = (const float*)d_in[5];
    const int N = in_sizes[0] / F_DIM;
    const int E = in_sizes[1] / 2;

    float* out = (float*)d_out;
    float* dg  = out + (size_t)N * NFOUT;
    u32* rank  = (u32*)d_ws;

    static bool attr_set = false;
    if (!attr_set) {
        (void)hipFuncSetAttribute((const void*)k_merge4,
                                  hipFuncAttributeMaxDynamicSharedMemorySize,
                                  160 * 1024);
        (void)hipFuncSetAttribute((const void*)k_filt_mfma,
                                  hipFuncAttributeMaxDynamicSharedMemorySize,
                                  160 * 1024);
        attr_set = true;
    }

    k_prep<<<(4 * N + 255) / 256, 256, 0, stream>>>(rank, N);

    const size_t w1t_need = (size_t)WS_W1T_OFF + 3ull * H_DIM * F_DIM * 2;
    if (ws_size >= w1t_need) {
        ushort_t* w1t = (ushort_t*)((char*)d_ws + WS_W1T_OFF);
        k_w1split<<<512, 256, 0, stream>>>(W1, w1t);
        k_filt_mfma<<<(N + 127) / 128, 512, SM_BYTES, stream>>>(X, w1t, b1, W2, b2, out, N);
    } else {
        k_filt<<<(N + BM - 1) / BM, 256, 0, stream>>>(X, W1, b1, W2, b2, out, N);
    }

    const int nchunk = (N + 255) / 256;
    const int njt    = (N + JTILE - 1) / JTILE;
    k_rank<<<nchunk * njt, 256, 0, stream>>>(out, rank, N, nchunk);
    k_merge4<<<4, 1024, (size_t)N * sizeof(u32), stream>>>(EI, rank, dg, N, E);
}

// Round 7
// 1457.286 us; speedup vs baseline: 1.2489x; 1.0998x over previous
//
#include <hip/hip_runtime.h>

typedef unsigned long long u64;
typedef unsigned int u32;
typedef unsigned short ushort_t;
typedef __attribute__((ext_vector_type(8))) short short8;
typedef __attribute__((ext_vector_type(4))) float fx4;

#define F_DIM 1024
#define H_DIM 2048
#define NFOUT 4
#define WS_W1T_OFF (1ull << 20)
#define WS_XS_OFF  (16ull << 20)
#define PB_BYTES   ((size_t)H_DIM * F_DIM * 2)   // 4 MB per W1 plane

// ---------------------------------------------------------------------------
// bf16 helpers (RNE) and 3-way split: x = p0+p1+p2, |p1|<=2^-9|x|, |p2|<=2^-18|x|
// ---------------------------------------------------------------------------
__device__ __forceinline__ ushort_t f2bf(float x)
{
    union { float f; u32 u; } c; c.f = x;
    u32 b = c.u;
    u32 r = b + 0x7FFFu + ((b >> 16) & 1u);
    return (ushort_t)(r >> 16);
}
__device__ __forceinline__ float bf2f(ushort_t h)
{
    union { u32 u; float f; } c; c.u = ((u32)h) << 16;
    return c.f;
}
__device__ __forceinline__ void split3(float x, ushort_t& u0, ushort_t& u1, ushort_t& u2)
{
    u0 = f2bf(x);
    float r1 = x - bf2f(u0);
    u1 = f2bf(r1);
    float r2 = r1 - bf2f(u1);
    u2 = f2bf(r2);
}

__device__ __forceinline__ void gload16(const void* g, void* l)
{
    __builtin_amdgcn_global_load_lds(
        (const __attribute__((address_space(1))) unsigned int*)g,
        (__attribute__((address_space(3))) unsigned int*)l, 16, 0, 0);
}

// ---------------------------------------------------------------------------
// k_w1split: W1[k][h] fp32 -> 3 bf16 planes, transposed AND pre-swizzled:
// w1t[p][h][chunk*128 + (cb ^ ((h&7)<<4))] = plane_p(h, k) for byte cb=2k%128.
// (Linear copy of this into LDS yields the XOR-swizzled tile; and the v3
// fallback's write-swizzle cancels against it bijectively.)
// ---------------------------------------------------------------------------
__global__ __launch_bounds__(256)
void k_w1split(const float* __restrict__ W1, ushort_t* __restrict__ w1t)
{
    __shared__ __align__(16) ushort_t LT[3][64][72];
    const int t = threadIdx.x;
    const int bk = blockIdx.x >> 5;
    const int bh = blockIdx.x & 31;
    const int k0 = bk * 64, h0 = bh * 64;
    const int kk = t >> 4, hb = (t & 15) * 4;
    #pragma unroll
    for (int j = 0; j < 4; j++) {
        int row = kk + j * 16;
        float4 v = *(const float4*)(W1 + (size_t)(k0 + row) * H_DIM + h0 + hb);
        float xs[4] = { v.x, v.y, v.z, v.w };
        #pragma unroll
        for (int c = 0; c < 4; c++) {
            ushort_t u0, u1, u2;
            split3(xs[c], u0, u1, u2);
            LT[0][hb + c][row] = u0;
            LT[1][hb + c][row] = u1;
            LT[2][hb + c][row] = u2;
        }
    }
    __syncthreads();
    const int hl = t >> 2, sg = t & 3;
    char* wb = (char*)w1t;
    const int hsw = (hl & 7) << 4;
    #pragma unroll
    for (int p = 0; p < 3; p++)
        #pragma unroll
        for (int q = 0; q < 2; q++) {
            int ks = sg * 16 + q * 8;
            *(short8*)(wb + (size_t)p * PB_BYTES + (size_t)(h0 + hl) * 2048
                       + bk * 128 + ((ks * 2) ^ hsw)) =
                *(const short8*)&LT[p][hl][ks];
        }
}

// ---------------------------------------------------------------------------
// k_xsplit: X[row][k] fp32 -> 3 bf16 planes, pre-swizzled like w1t.
// One row per block; thread t handles k = 4t..4t+3 (8 bytes, 8B-aligned XOR).
// ---------------------------------------------------------------------------
__global__ __launch_bounds__(256)
void k_xsplit(const float* __restrict__ X, ushort_t* __restrict__ xs,
              int N, int Npad)
{
    const int row = blockIdx.x;
    if (row >= N) return;
    const int t = threadIdx.x;
    float4 v = *(const float4*)(X + (size_t)row * F_DIM + t * 4);
    const int swz = (row & 7) << 4;
    const int off = ((t * 8) & ~127) | (((t * 8) & 127) ^ swz);
    const size_t PA = (size_t)Npad * 2048;
    char* base = (char*)xs + (size_t)row * 2048 + off;
    float in[4] = { v.x, v.y, v.z, v.w };
    ushort4 u0, u1, u2;
    ushort_t* p0 = (ushort_t*)&u0; ushort_t* p1 = (ushort_t*)&u1; ushort_t* p2 = (ushort_t*)&u2;
    #pragma unroll
    for (int j = 0; j < 4; j++) split3(in[j], p0[j], p1[j], p2[j]);
    *(ushort4*)(base)          = u0;
    *(ushort4*)(base + PA)     = u1;
    *(ushort4*)(base + 2 * PA) = u2;
}

// ---------------------------------------------------------------------------
// k_filt_mfma4: block 80 rows x 256 hid (grid = N/80 = 250 -> 98% CU fill),
// 512 threads = 8 waves, each 80x32 (5x2 frags). Split-6 bf16 MFMA.
// Staging = global_load_lds 16B from pre-swizzled planes (linear dest ->
// swizzled LDS tile). LDS: A 30K | B 96K | W2 4K = 130 KB. GEMM2 fused.
// ---------------------------------------------------------------------------
__device__ __forceinline__ fx4 mfma16(short8 a, short8 b, fx4 c)
{
    return __builtin_amdgcn_mfma_f32_16x16x32_bf16(a, b, c, 0, 0, 0);
}

#define A4_BYTES (3 * 80 * 128)      // 30720
#define B4_BYTES (3 * 256 * 128)     // 98304
#define W24_OFF  (A4_BYTES + B4_BYTES)
#define SM4_BYTES (W24_OFF + 256 * 4 * 4)
#define HP4 260

__global__ __launch_bounds__(512, 1)
void k_filt_mfma4(const ushort_t* __restrict__ xs, const ushort_t* __restrict__ w1t,
                  const float* __restrict__ b1, const float* __restrict__ W2,
                  const float* __restrict__ b2, float* __restrict__ out,
                  int N, int Npad)
{
    extern __shared__ char smem[];
    char* Ac = smem;
    char* Bc = smem + A4_BYTES;
    float* W2s = (float*)(smem + W24_OFF);
    float* hid = (float*)smem;       // overlay: 80*260*4 = 83200 <= 129024

    const int t = threadIdx.x;
    const int lane = t & 63;
    const int w = t >> 6;
    const int wc = w * 32;           // wave hid-col base
    const int r0 = blockIdx.x * 80;
    const int l15 = lane & 15, l4 = lane >> 4;
    const int fsw = (l15 & 7) << 4;

    const char* xsb = (const char*)xs;
    const char* w1b = (const char*)w1t;
    const size_t PA = (size_t)Npad * 2048;
    const int laneoff = (lane >> 3) * 2048 + ((lane & 7) << 4);

    const int orow = t >> 2;         // GEMM2 owner (<80 active)
    const int onf  = t & 3;

    fx4 acc[5][2];
    #pragma unroll
    for (int i = 0; i < 5; i++)
        #pragma unroll
        for (int j = 0; j < 2; j++) acc[i][j] = (fx4)(0.f);
    float pacc = 0.f;

    for (int it = 0; it < 128; ++it) {
        const int hc = it >> 4, kc = it & 15;

        __syncthreads();   // prior readers of Ac/Bc (MFMA or GEMM2) done

        // ---- stage A+B via global_load_lds (126 granules, wave-cyclic) ----
        for (int g = w; g < 126; g += 8) {
            char* ldsb; const char* src;
            if (g < 30) {
                const int p = g / 10, rg = g - p * 10;
                ldsb = Ac + p * 10240 + rg * 1024;
                src  = xsb + (size_t)p * PA + (size_t)(r0 + rg * 8) * 2048 + kc * 128;
            } else {
                const int gb = g - 30;
                const int p = gb >> 5, rg = gb & 31;
                ldsb = Bc + p * 32768 + rg * 1024;
                src  = w1b + (size_t)p * PB_BYTES + (size_t)(hc * 256 + rg * 8) * 2048 + kc * 128;
            }
            gload16(src + laneoff, ldsb);
        }
        if (kc == 0 && t < 256)
            *(float4*)&W2s[t * 4] = *(const float4*)(W2 + ((size_t)hc * 256 + t) * NFOUT);

        __syncthreads();   // vmcnt drained by compiler before barrier -> tile ready

        // ---- MFMA: split-6, 80x32 wave tile ----
        #pragma unroll
        for (int sub = 0; sub < 2; ++sub) {
            const int kb = (sub * 64 + l4 * 16) ^ fsw;
            short8 b[2][3];
            #pragma unroll
            for (int cf = 0; cf < 2; ++cf) {
                const int hrow = wc + cf * 16 + l15;
                #pragma unroll
                for (int p = 0; p < 3; p++)
                    b[cf][p] = *(const short8*)(Bc + p * 32768 + hrow * 128 + kb);
            }
            #pragma unroll
            for (int rr = 0; rr < 5; ++rr) {
                const int row = rr * 16 + l15;
                short8 a0 = *(const short8*)(Ac + 0 * 10240 + row * 128 + kb);
                short8 a1 = *(const short8*)(Ac + 1 * 10240 + row * 128 + kb);
                short8 a2 = *(const short8*)(Ac + 2 * 10240 + row * 128 + kb);
                #pragma unroll
                for (int cf = 0; cf < 2; ++cf) {
                    fx4 c = acc[rr][cf];
                    c = mfma16(a0, b[cf][0], c);
                    c = mfma16(a0, b[cf][1], c);
                    c = mfma16(a1, b[cf][0], c);
                    c = mfma16(a0, b[cf][2], c);
                    c = mfma16(a1, b[cf][1], c);
                    c = mfma16(a2, b[cf][0], c);
                    acc[rr][cf] = c;
                }
            }
        }

        if (kc == 15) {
            __syncthreads();   // MFMA reads done; hid overlays Ac|Bc
            // ---- hid: +b1, relu (C/D: col=lane&15, row=(lane>>4)*4+reg) ----
            #pragma unroll
            for (int rr = 0; rr < 5; ++rr)
                #pragma unroll
                for (int cf = 0; cf < 2; ++cf) {
                    const int hl = wc + cf * 16 + l15;
                    const float bias1 = b1[hc * 256 + hl];
                    #pragma unroll
                    for (int g = 0; g < 4; g++) {
                        const int rl = rr * 16 + l4 * 4 + g;
                        hid[rl * HP4 + hl] = fmaxf(acc[rr][cf][g] + bias1, 0.f);
                    }
                    acc[rr][cf] = (fx4)(0.f);
                }
            __syncthreads();
            // ---- GEMM2: thread (row, nf) full 256-h ascending chain ----
            if (orow < 80) {
                const float* hp = hid + orow * HP4;
                #pragma unroll 16
                for (int j = 0; j < 256; j++)
                    pacc = fmaf(hp[j], W2s[j * 4 + onf], pacc);
            }
        }
    }

    if (orow < 80) {
        const int rg = r0 + orow;
        if (rg < N) out[(size_t)rg * NFOUT + onf] = pacc + b2[onf];
    }
}

// ---------------------------------------------------------------------------
// k_filt_mfma3: R6 kernel (fallback tier if ws < xsplit need). Works
// unchanged with pre-swizzled w1t: its write-swizzle cancels bijectively.
// ---------------------------------------------------------------------------
#define AP_BYTES (3 * 128 * 128)
#define BP_BYTES (3 * 256 * 128)
#define W2_OFF   (AP_BYTES + BP_BYTES)
#define SM_BYTES (W2_OFF + 256 * 4 * 4)
#define HPITCH 260

__global__ __launch_bounds__(512, 2)
void k_filt_mfma3(const float* __restrict__ X, const ushort_t* __restrict__ w1t,
                  const float* __restrict__ b1, const float* __restrict__ W2,
                  const float* __restrict__ b2, float* __restrict__ out, int N)
{
    extern __shared__ char smem[];
    char* Ac = smem;
    char* Bc = smem + AP_BYTES;
    float* W2s = (float*)(smem + W2_OFF);
    float* hid = (float*)smem;

    const int t = threadIdx.x;
    const int lane = t & 63;
    const int w = t >> 6;
    const int wr = (w >> 2) * 64;
    const int wc = (w & 3) * 64;
    const int r0 = blockIdx.x * 128;
    const int l15 = lane & 15, l4 = lane >> 4;
    const int fsw = (l15 & 7) << 4;

    const int arow = t >> 2;
    const int aq   = (t & 3);
    const bool arow_ok = (r0 + arow) < N;
    const int brow = t >> 1;
    const int bseg = (t & 1) * 64;
    const int orow = t >> 2;
    const int onf  = t & 3;

    float Afl[16];
    short8 Bv[12];
    fx4 acc[4][4];
    float pacc = 0.f;
    #pragma unroll
    for (int i = 0; i < 4; i++)
        #pragma unroll
        for (int j = 0; j < 4; j++) acc[i][j] = (fx4)(0.f);

    {
        if (arow_ok) {
            #pragma unroll
            for (int q = 0; q < 4; q++) {
                float4 v = *(const float4*)(X + (size_t)(r0 + arow) * F_DIM + aq * 16 + q * 4);
                Afl[q * 4 + 0] = v.x; Afl[q * 4 + 1] = v.y;
                Afl[q * 4 + 2] = v.z; Afl[q * 4 + 3] = v.w;
            }
        } else {
            #pragma unroll
            for (int j = 0; j < 16; j++) Afl[j] = 0.f;
        }
        #pragma unroll
        for (int p = 0; p < 3; p++)
            #pragma unroll
            for (int q = 0; q < 4; q++)
                Bv[p * 4 + q] = *(const short8*)((const char*)w1t + (size_t)p * PB_BYTES
                                 + (size_t)brow * 2048 + bseg + q * 16);
    }

    for (int it = 0; it < 128; ++it) {
        const int hc = it >> 4, kc = it & 15;

        ushort_t s0[16], s1[16], s2[16];
        #pragma unroll
        for (int j = 0; j < 16; j++) split3(Afl[j], s0[j], s1[j], s2[j]);

        __syncthreads();

        {
            const int aswz = (arow & 7) << 4;
            #pragma unroll
            for (int p = 0; p < 3; p++) {
                const ushort_t* sp = (p == 0) ? s0 : (p == 1) ? s1 : s2;
                #pragma unroll
                for (int h = 0; h < 2; h++) {
                    short8 pk;
                    #pragma unroll
                    for (int i = 0; i < 8; i++) pk[i] = (short)sp[h * 8 + i];
                    *(short8*)(Ac + p * 16384 + arow * 128 + ((aq * 32 + h * 16) ^ aswz)) = pk;
                }
            }
            const int bswz = (brow & 7) << 4;
            #pragma unroll
            for (int p = 0; p < 3; p++)
                #pragma unroll
                for (int q = 0; q < 4; q++)
                    *(short8*)(Bc + p * 32768 + brow * 128 + ((bseg + q * 16) ^ bswz)) = Bv[p * 4 + q];
            if (kc == 0 && t < 256)
                *(float4*)&W2s[t * 4] = *(const float4*)(W2 + ((size_t)hc * 256 + t) * NFOUT);
        }

        if (it + 1 < 128) {
            const int hn = (it + 1) >> 4, kn = (it + 1) & 15;
            if (arow_ok) {
                #pragma unroll
                for (int q = 0; q < 4; q++) {
                    float4 v = *(const float4*)(X + (size_t)(r0 + arow) * F_DIM + kn * 64 + aq * 16 + q * 4);
                    Afl[q * 4 + 0] = v.x; Afl[q * 4 + 1] = v.y;
                    Afl[q * 4 + 2] = v.z; Afl[q * 4 + 3] = v.w;
                }
            }
            #pragma unroll
            for (int p = 0; p < 3; p++)
                #pragma unroll
                for (int q = 0; q < 4; q++)
                    Bv[p * 4 + q] = *(const short8*)((const char*)w1t + (size_t)p * PB_BYTES
                                     + (size_t)(hn * 256 + brow) * 2048 + kn * 128 + bseg + q * 16);
        }

        __syncthreads();

        #pragma unroll
        for (int sub = 0; sub < 2; ++sub) {
            const int kb = sub * 64 + l4 * 16;
            short8 b[4][3];
            #pragma unroll
            for (int cf = 0; cf < 4; ++cf) {
                const int hrow = wc + cf * 16 + l15;
                #pragma unroll
                for (int p = 0; p < 3; p++)
                    b[cf][p] = *(const short8*)(Bc + p * 32768 + hrow * 128 + (kb ^ fsw));
            }
            #pragma unroll
            for (int rr = 0; rr < 4; ++rr) {
                const int row = wr + rr * 16 + l15;
                short8 a0 = *(const short8*)(Ac + 0 * 16384 + row * 128 + (kb ^ fsw));
                short8 a1 = *(const short8*)(Ac + 1 * 16384 + row * 128 + (kb ^ fsw));
                short8 a2 = *(const short8*)(Ac + 2 * 16384 + row * 128 + (kb ^ fsw));
                #pragma unroll
                for (int cf = 0; cf < 4; ++cf) {
                    fx4 c = acc[rr][cf];
                    c = mfma16(a0, b[cf][0], c);
                    c = mfma16(a0, b[cf][1], c);
                    c = mfma16(a1, b[cf][0], c);
                    c = mfma16(a0, b[cf][2], c);
                    c = mfma16(a1, b[cf][1], c);
                    c = mfma16(a2, b[cf][0], c);
                    acc[rr][cf] = c;
                }
            }
        }

        if (kc == 15) {
            __syncthreads();
            #pragma unroll
            for (int rr = 0; rr < 4; ++rr)
                #pragma unroll
                for (int cf = 0; cf < 4; ++cf) {
                    const int hl = wc + cf * 16 + l15;
                    const float bias1 = b1[hc * 256 + hl];
                    #pragma unroll
                    for (int g = 0; g < 4; g++) {
                        const int rl = wr + rr * 16 + l4 * 4 + g;
                        hid[rl * HPITCH + hl] = fmaxf(acc[rr][cf][g] + bias1, 0.f);
                    }
                    acc[rr][cf] = (fx4)(0.f);
                }
            __syncthreads();
            {
                const float* hp = hid + orow * HPITCH;
                #pragma unroll 16
                for (int j = 0; j < 256; j++)
                    pacc = fmaf(hp[j], W2s[j * 4 + onf], pacc);
            }
        }
    }

    {
        const int rg = r0 + orow;
        if (rg < N) out[(size_t)rg * NFOUT + onf] = pacc + b2[onf];
    }
}

// ---------------------------------------------------------------------------
// FALLBACK fp32 k_filt (only if ws too small for any plane buffer)
// ---------------------------------------------------------------------------
#define BM 64
#define BH 64
#define KCH 64
#define LROW 68

__global__ __launch_bounds__(256, 2)
void k_filt(const float* __restrict__ X, const float* __restrict__ W1,
            const float* __restrict__ b1, const float* __restrict__ W2,
            const float* __restrict__ b2, float* __restrict__ out, int N)
{
    __shared__ float Xs[KCH * LROW];
    __shared__ float Ws[KCH * LROW];
    __shared__ float W2s[BH * NFOUT];
    const int t = threadIdx.x;
    const int r0 = blockIdx.x * BM;
    const int tr = t >> 4, tc = t & 15;
    const int orow = t >> 2, onf = t & 3;
    float fchain = 0.0f;
    for (int hc = 0; hc < H_DIM; hc += BH) {
        float acc[4][4];
        #pragma unroll
        for (int i = 0; i < 4; i++)
            #pragma unroll
            for (int j = 0; j < 4; j++) acc[i][j] = 0.0f;
        for (int kc = 0; kc < F_DIM; kc += KCH) {
            {
                const int rowq = t >> 4, kkq = t & 15;
                float xv[4][4];
                #pragma unroll
                for (int j = 0; j < 4; j++) {
                    int r = r0 + rowq * 4 + j;
                    float4 v = (r < N) ? *(const float4*)(X + (size_t)r * F_DIM + kc + kkq * 4)
                                       : make_float4(0.f, 0.f, 0.f, 0.f);
                    xv[j][0] = v.x; xv[j][1] = v.y; xv[j][2] = v.z; xv[j][3] = v.w;
                }
                #pragma unroll
                for (int j = 0; j < 4; j++)
                    *(float4*)&Xs[(kkq * 4 + j) * LROW + rowq * 4] =
                        make_float4(xv[0][j], xv[1][j], xv[2][j], xv[3][j]);
            }
            {
                const int hq = t & 15;
                #pragma unroll
                for (int q = 0; q < 4; q++) {
                    int kk = (t >> 4) + q * 16;
                    *(float4*)&Ws[kk * LROW + hq * 4] =
                        *(const float4*)(W1 + (size_t)(kc + kk) * H_DIM + hc + hq * 4);
                }
            }
            __syncthreads();
            #pragma unroll 8
            for (int kk = 0; kk < KCH; kk++) {
                float4 xv = *(float4*)&Xs[kk * LROW + tr * 4];
                float4 wv = *(float4*)&Ws[kk * LROW + tc * 4];
                acc[0][0] = fmaf(xv.x, wv.x, acc[0][0]); acc[0][1] = fmaf(xv.x, wv.y, acc[0][1]);
                acc[0][2] = fmaf(xv.x, wv.z, acc[0][2]); acc[0][3] = fmaf(xv.x, wv.w, acc[0][3]);
                acc[1][0] = fmaf(xv.y, wv.x, acc[1][0]); acc[1][1] = fmaf(xv.y, wv.y, acc[1][1]);
                acc[1][2] = fmaf(xv.y, wv.z, acc[1][2]); acc[1][3] = fmaf(xv.y, wv.w, acc[1][3]);
                acc[2][0] = fmaf(xv.z, wv.x, acc[2][0]); acc[2][1] = fmaf(xv.z, wv.y, acc[2][1]);
                acc[2][2] = fmaf(xv.z, wv.z, acc[2][2]); acc[2][3] = fmaf(xv.z, wv.w, acc[2][3]);
                acc[3][0] = fmaf(xv.w, wv.x, acc[3][0]); acc[3][1] = fmaf(xv.w, wv.y, acc[3][1]);
                acc[3][2] = fmaf(xv.w, wv.z, acc[3][2]); acc[3][3] = fmaf(xv.w, wv.w, acc[3][3]);
            }
            __syncthreads();
        }
        {
            float4 bv = *(const float4*)(b1 + hc + tc * 4);
            #pragma unroll
            for (int i = 0; i < 4; i++) {
                float4 hv;
                hv.x = fmaxf(acc[i][0] + bv.x, 0.f);
                hv.y = fmaxf(acc[i][1] + bv.y, 0.f);
                hv.z = fmaxf(acc[i][2] + bv.z, 0.f);
                hv.w = fmaxf(acc[i][3] + bv.w, 0.f);
                *(float4*)&Ws[(tr * 4 + i) * LROW + tc * 4] = hv;
            }
            if (t < BH)
                *(float4*)&W2s[t * 4] = *(const float4*)(W2 + (size_t)(hc + t) * NFOUT);
        }
        __syncthreads();
        #pragma unroll 16
        for (int hh = 0; hh < BH; hh++)
            fchain = fmaf(Ws[orow * LROW + hh], W2s[hh * 4 + onf], fchain);
        __syncthreads();
    }
    {
        int r = r0 + orow;
        if (r < N) out[(size_t)r * NFOUT + onf] = fchain + b2[onf];
    }
}

// ---------------------------------------------------------------------------
__global__ void k_prep(u32* __restrict__ rank, int N)
{
    int g = blockIdx.x * blockDim.x + threadIdx.x;
    if (g < 4 * N) rank[g] = 0u;
}

// ---------------------------------------------------------------------------
#define JTILE 2048

__global__ __launch_bounds__(256)
void k_rank(const float* __restrict__ filt, u32* __restrict__ rank,
            int N, int nchunk)
{
    __shared__ float4 lds[JTILE];
    const int chunk = blockIdx.x % nchunk;
    const int jslice = blockIdx.x / nchunk;
    const int jt = jslice * JTILE;
    const int i = chunk * 256 + threadIdx.x;
    const bool iok = i < N;
    float4 vi = iok ? *(const float4*)(filt + (size_t)i * 4)
                    : make_float4(0.f, 0.f, 0.f, 0.f);
    for (int s = 0; s < JTILE; s += 256) {
        int j = jt + s + threadIdx.x;
        lds[s + threadIdx.x] = (j < N)
            ? *(const float4*)(filt + (size_t)j * 4)
            : make_float4(INFINITY, INFINITY, INFINITY, INFINITY);
    }
    __syncthreads();
    int c0 = 0, c1 = 0, c2 = 0, c3 = 0;
    #pragma unroll 4
    for (int jj = 0; jj < JTILE; jj++) {
        float4 vj = lds[jj];
        int j = jt + jj;
        bool jlt = j < i;
        c0 += (vj.x < vi.x) || (vj.x == vi.x && jlt);
        c1 += (vj.y < vi.y) || (vj.y == vi.y && jlt);
        c2 += (vj.z < vi.z) || (vj.z == vi.z && jlt);
        c3 += (vj.w < vi.w) || (vj.w == vi.w && jlt);
    }
    if (iok) {
        atomicAdd(&rank[0 * N + i], (u32)c0);
        atomicAdd(&rank[1 * N + i], (u32)c1);
        atomicAdd(&rank[2 * N + i], (u32)c2);
        atomicAdd(&rank[3 * N + i], (u32)c3);
    }
}

// ---------------------------------------------------------------------------
// Triplet merge tree in LDS (one 1024-thr block per filtration)
// ---------------------------------------------------------------------------
__device__ __forceinline__ u32 lds_aload(u32* p)
{
    return __hip_atomic_load(p, __ATOMIC_RELAXED, __HIP_MEMORY_SCOPE_WORKGROUP);
}

__device__ __forceinline__ u32 rep_walk32(u32* S, u32 u, u32 t, u32& sv_out)
{
    u32 sv = lds_aload(&S[u]);
    while ((sv >> 16) <= t) {
        u = sv & 0xFFFFu;
        sv = lds_aload(&S[u]);
    }
    sv_out = sv;
    return u;
}

__device__ void do_merge32(u32* S, u32 u, u32 v, u32 t)
{
    for (int guard = 0; guard < (1 << 22); guard++) {
        u32 svu, svv;
        u = rep_walk32(S, u, t, svu);
        v = rep_walk32(S, v, t, svv);
        if (u == v) return;
        if (u < v) { u32 tm = u; u = v; v = tm; u32 ts = svu; svu = svv; svv = ts; }
        u32 s = svu >> 16;
        if (s <= t) continue;
        u32 des = (t << 16) | v;
        u32 old = atomicCAS(&S[u], svu, des);
        if (old == svu) {
            if (s == 0xFFFFu) return;
            u = v; v = old & 0xFFFFu;
            t = s;
        }
    }
}

__global__ __launch_bounds__(1024, 1)
void k_merge4(const int* __restrict__ eidx, const u32* __restrict__ rank,
              float* __restrict__ dg, int N, int E)
{
    extern __shared__ u32 S[];
    const int f = blockIdx.x;
    const u32* rk = rank + (size_t)f * N;

    for (int u = threadIdx.x; u < N; u += blockDim.x)
        S[u] = (0xFFFFu << 16) | (u32)u;
    __syncthreads();

    for (int e = threadIdx.x; e < E; e += blockDim.x) {
        u32 a = rk[eidx[e]];
        u32 b = rk[eidx[E + e]];
        if (a < b) do_merge32(S, a, b, b);
    }
    __syncthreads();

    for (int r = threadIdx.x; r < N; r += blockDim.x) {
        u32 s = S[r] >> 16;
        float death = (s == 0xFFFFu) ? 3.0e38f : (float)s;
        dg[(size_t)f * N * 2 + (size_t)r * 2 + 0] = (float)r;
        dg[(size_t)f * N * 2 + (size_t)r * 2 + 1] = death;
    }
}

// ---------------------------------------------------------------------------
extern "C" void kernel_launch(void* const* d_in, const int* in_sizes, int n_in,
                              void* d_out, int out_size, void* d_ws, size_t ws_size,
                              hipStream_t stream)
{
    const float* X  = (const float*)d_in[0];
    const int*   EI = (const int*)d_in[1];
    const float* W1 = (const float*)d_in[2];
    const float* b1 = (const float*)d_in[3];
    const float* W2 = (const float*)d_in[4];
    const float* b2 = (const float*)d_in[5];
    const int N = in_sizes[0] / F_DIM;
    const int E = in_sizes[1] / 2;

    float* out = (float*)d_out;
    float* dg  = out + (size_t)N * NFOUT;
    u32* rank  = (u32*)d_ws;

    static bool attr_set = false;
    if (!attr_set) {
        (void)hipFuncSetAttribute((const void*)k_merge4,
                                  hipFuncAttributeMaxDynamicSharedMemorySize, 160 * 1024);
        (void)hipFuncSetAttribute((const void*)k_filt_mfma3,
                                  hipFuncAttributeMaxDynamicSharedMemorySize, 160 * 1024);
        (void)hipFuncSetAttribute((const void*)k_filt_mfma4,
                                  hipFuncAttributeMaxDynamicSharedMemorySize, 160 * 1024);
        attr_set = true;
    }

    k_prep<<<(4 * N + 255) / 256, 256, 0, stream>>>(rank, N);

    const int Npad = ((N + 79) / 80) * 80;
    const size_t need_w1t = WS_W1T_OFF + 3ull * PB_BYTES;
    const size_t need_xs  = WS_XS_OFF + 3ull * (size_t)Npad * 2048;

    if (ws_size >= need_xs) {
        ushort_t* w1t = (ushort_t*)((char*)d_ws + WS_W1T_OFF);
        ushort_t* xsp = (ushort_t*)((char*)d_ws + WS_XS_OFF);
        k_w1split<<<512, 256, 0, stream>>>(W1, w1t);
        k_xsplit<<<N, 256, 0, stream>>>(X, xsp, N, Npad);
        k_filt_mfma4<<<Npad / 80, 512, SM4_BYTES, stream>>>(xsp, w1t, b1, W2, b2, out, N, Npad);
    } else if (ws_size >= need_w1t) {
        ushort_t* w1t = (ushort_t*)((char*)d_ws + WS_W1T_OFF);
        k_w1split<<<512, 256, 0, stream>>>(W1, w1t);
        k_filt_mfma3<<<(N + 127) / 128, 512, SM_BYTES, stream>>>(X, w1t, b1, W2, b2, out, N);
    } else {
        k_filt<<<(N + BM - 1) / BM, 256, 0, stream>>>(X, W1, b1, W2, b2, out, N);
    }

    const int nchunk = (N + 255) / 256;
    const int njt    = (N + JTILE - 1) / JTILE;
    k_rank<<<nchunk * njt, 256, 0, stream>>>(out, rank, N, nchunk);
    k_merge4<<<4, 1024, (size_t)N * sizeof(u32), stream>>>(EI, rank, dg, N, E);
}